// Round 23
// baseline (443.354 us; speedup 1.0000x reference)
//
#include <hip/hip_runtime.h>

typedef unsigned int u32;
typedef unsigned short u16;
typedef __attribute__((ext_vector_type(8))) short bf16x8;
typedef __attribute__((ext_vector_type(4))) float f32x4;

__device__ __forceinline__ u16 f2b(float f){
  u32 x = __float_as_uint(f);
  u32 r = (x + 0x7fffu + ((x >> 16) & 1u)) >> 16;
  return (u16)r;
}
__device__ __forceinline__ float b2f(u16 h){ return __uint_as_float((u32)h << 16); }
__device__ __forceinline__ float bl(u32 u){ return __uint_as_float(u << 16); }
__device__ __forceinline__ float bh(u32 u){ return __uint_as_float(u & 0xffff0000u); }

// ---------- preprocessing ----------

__global__ void k_detect(const u32* __restrict__ ei, int n, u32* __restrict__ flag){
  int t = blockIdx.x * blockDim.x + threadIdx.x;
  u32 v = 0;
  if (t < n) v = ei[2 * t + 1];
  unsigned long long b = __ballot(v != 0u);
  if ((threadIdx.x & 63) == 0 && b) atomicOr(flag, 1u);
}

// fused: index convert + degree histogram
__global__ void k_convhist(const int* __restrict__ ei, int* __restrict__ src, int* __restrict__ dst,
                           int* __restrict__ deg, int E, const u32* __restrict__ flag){
  int e = blockIdx.x * blockDim.x + threadIdx.x;
  if (e >= E) return;
  bool is64 = (*flag == 0u);
  int s, d;
  if (is64){ s = ei[2 * e]; d = ei[2 * (E + e)]; }
  else     { s = ei[e];     d = ei[E + e]; }
  src[e] = s; dst[e] = d;
  atomicAdd(&deg[d], 1);
}

// hierarchical scan; block 0 also zeroes the pad tails
__global__ __launch_bounds__(256) void k_scan1(const int* __restrict__ deg, int* __restrict__ bsum, int n,
                                               int* __restrict__ ssrc, int* __restrict__ sdst,
                                               u16* __restrict__ ea2s_pad, int E){
  int b = blockIdx.x, t = threadIdx.x, lane = t & 63, wv = t >> 6;
  if (b == 0){
    if (t < 64){ ssrc[E + t] = 0; sdst[E + t] = 0; }
    ((uint4*)ea2s_pad)[t] = make_uint4(0, 0, 0, 0);
  }
  int i0 = b * 1024 + t * 4;
  int4 v = make_int4(0,0,0,0);
  if (i0 + 3 < n) v = *(const int4*)(deg + i0);
  else { if (i0 < n) v.x = deg[i0]; if (i0+1 < n) v.y = deg[i0+1]; if (i0+2 < n) v.z = deg[i0+2]; }
  int s = v.x + v.y + v.z + v.w;
  #pragma unroll
  for (int off = 1; off < 64; off <<= 1) s += __shfl_xor(s, off);
  __shared__ int ws[4];
  if (lane == 0) ws[wv] = s;
  __syncthreads();
  if (t == 0) bsum[b] = ws[0] + ws[1] + ws[2] + ws[3];
}

__global__ __launch_bounds__(1024) void k_scan2(int* __restrict__ bsum, int nb, int* __restrict__ segN){
  int t = threadIdx.x, lane = t & 63, w = t >> 6;
  int v = (t < nb) ? bsum[t] : 0;
  int x = v;
  #pragma unroll
  for (int off = 1; off < 64; off <<= 1){
    int y = __shfl_up(x, off);
    if (lane >= off) x += y;
  }
  __shared__ int wsum[16];
  if (lane == 63) wsum[w] = x;
  __syncthreads();
  if (w == 0 && lane < 16){
    int sv = wsum[lane];
    #pragma unroll
    for (int off = 1; off < 16; off <<= 1){
      int y = __shfl_up(sv, off);
      if (lane >= off) sv += y;
    }
    wsum[lane] = sv;
  }
  __syncthreads();
  int woff = (w > 0) ? wsum[w - 1] : 0;
  if (t < nb) bsum[t] = woff + x - v;
  if (t == 0) *segN = wsum[15];
}

__global__ __launch_bounds__(256) void k_scan3(const int* __restrict__ deg, const int* __restrict__ bsum,
                                               int* __restrict__ seg, int n){
  int b = blockIdx.x, t = threadIdx.x, lane = t & 63, wv = t >> 6;
  int i0 = b * 1024 + t * 4;
  int4 v = make_int4(0,0,0,0);
  if (i0 + 3 < n) v = *(const int4*)(deg + i0);
  else { if (i0 < n) v.x = deg[i0]; if (i0+1 < n) v.y = deg[i0+1]; if (i0+2 < n) v.z = deg[i0+2]; }
  int s = v.x + v.y + v.z + v.w;
  int x = s;
  #pragma unroll
  for (int off = 1; off < 64; off <<= 1){
    int y = __shfl_up(x, off);
    if (lane >= off) x += y;
  }
  __shared__ int ws[4];
  if (lane == 63) ws[wv] = x;
  __syncthreads();
  int woff = 0;
  #pragma unroll
  for (int k = 0; k < 4; k++) if (k < wv) woff += ws[k];
  int base = bsum[b] + woff + (x - s);
  if (i0 < n)     seg[i0]     = base;
  if (i0+1 < n)   seg[i0+1]   = base + v.x;
  if (i0+2 < n)   seg[i0+2]   = base + v.x + v.y;
  if (i0+3 < n)   seg[i0+3]   = base + v.x + v.y + v.z;
}

// scatter: 12B {src, dst, eid} per edge to sorted position
__global__ void k_scatter(const int* __restrict__ src, const int* __restrict__ dst,
                          const int* __restrict__ seg, int* __restrict__ cur,
                          int* __restrict__ ssrc, int* __restrict__ sdst,
                          int* __restrict__ seid, int E){
  int e = blockIdx.x * blockDim.x + threadIdx.x;
  if (e >= E) return;
  int d = dst[e];
  int pos = seg[d] + atomicAdd(&cur[d], 1);
  ssrc[pos] = src[e];
  sdst[pos] = d;
  seid[pos] = e;
}

// sort + convert: read eattr f32 rows via seid, write dst-sorted bf16 rows coalesced
__global__ void k_sortb(const int* __restrict__ seid, const float* __restrict__ eattr,
                        u16* __restrict__ ea2s, int E){
  int t = blockIdx.x * blockDim.x + threadIdx.x;
  int e = t >> 3, j = t & 7;
  if (e >= E) return;
  int eid = seid[e];
  float4 v = *(const float4*)(eattr + (size_t)eid * 32 + j * 4);
  u32 p0 = (u32)f2b(v.x) | ((u32)f2b(v.y) << 16);
  u32 p1 = (u32)f2b(v.z) | ((u32)f2b(v.w) << 16);
  *(uint2*)(ea2s + (size_t)e * 32 + j * 4) = make_uint2(p0, p1);
}

// ---------- W prep: transpose + bf16 hi/lo split ----------
__global__ __launch_bounds__(256) void k_prepw(
    const float* __restrict__ W0, const float* __restrict__ W1, const float* __restrict__ W2,
    const float* __restrict__ W3, const float* __restrict__ W4, const float* __restrict__ W5,
    u16* __restrict__ WtH, u16* __restrict__ WtL)
{
  int mat = blockIdx.z;
  const float* W = (mat == 0) ? W0 : (mat == 1) ? W1 : (mat == 2) ? W2 :
                   (mat == 3) ? W3 : (mat == 4) ? W4 : W5;
  __shared__ float tile[32][33];
  int kt = blockIdx.x * 32, ct = blockIdx.y * 32;
  int tr = threadIdx.x & 31, ti = threadIdx.x >> 5;
  #pragma unroll
  for (int j = 0; j < 4; j++){
    int kk = ti + 8 * j;
    tile[kk][tr] = W[(size_t)(kt + kk) * 128 + ct + tr];
  }
  __syncthreads();
  #pragma unroll
  for (int j = 0; j < 4; j++){
    int cc = ti + 8 * j;
    float v = tile[tr][cc];
    u16 hi = f2b(v);
    u16 lo = f2b(v - b2f(hi));
    size_t o = (size_t)mat * 16384 + (size_t)(ct + cc) * 128 + kt + tr;
    WtH[o] = hi;
    WtL[o] = lo;
  }
}

// ---------- node transform via MFMA (bf16x3 split), BOTH mats in one block ----------
__global__ __launch_bounds__(512) void k_gemm2(
    const float* __restrict__ A,
    const u16* __restrict__ WtH, const u16* __restrict__ WtL,
    u16* __restrict__ xlb, u16* __restrict__ xrb, int nrows)
{
  __shared__ u16 sAH[64][32], sAL[64][32];
  __shared__ u16 sWH[256][32], sWL[256][32];
  int t = threadIdx.x, wv = t >> 6, lane = t & 63;
  int col = lane & 15, kg = lane >> 4;
  int mat = wv >> 2, cq = wv & 3;
  int r0 = blockIdx.x * 64;

  f32x4 acc[4][2];
  #pragma unroll
  for (int m = 0; m < 4; m++)
    #pragma unroll
    for (int n = 0; n < 2; n++)
      acc[m][n] = (f32x4){0.f, 0.f, 0.f, 0.f};

  int ar = t >> 3, ak = (t & 7) << 2;
  int wmt = t >> 8, wtt = t & 255;
  int wc = wtt >> 1, wk = (wtt & 1) << 4;

  for (int kh = 0; kh < 4; kh++){
    __syncthreads();
    {
      int gr = r0 + ar;
      const float* ap = A + (size_t)gr * 128 + kh * 32 + ak;
      float4 va = {0,0,0,0};
      if (gr < nrows) va = *(const float4*)ap;
      u16 h0 = f2b(va.x), h1 = f2b(va.y), h2 = f2b(va.z), h3 = f2b(va.w);
      u16 l0 = f2b(va.x - b2f(h0)), l1 = f2b(va.y - b2f(h1));
      u16 l2 = f2b(va.z - b2f(h2)), l3 = f2b(va.w - b2f(h3));
      *(uint2*)&sAH[ar][ak] = make_uint2((u32)h0 | ((u32)h1 << 16), (u32)h2 | ((u32)h3 << 16));
      *(uint2*)&sAL[ar][ak] = make_uint2((u32)l0 | ((u32)l1 << 16), (u32)l2 | ((u32)l3 << 16));
    }
    {
      const u16* gh = WtH + (size_t)wmt * 16384 + (size_t)wc * 128 + kh * 32 + wk;
      const u16* gl = WtL + (size_t)wmt * 16384 + (size_t)wc * 128 + kh * 32 + wk;
      uint4 h0 = *(const uint4*)gh, h1 = *(const uint4*)(gh + 8);
      uint4 l0 = *(const uint4*)gl, l1 = *(const uint4*)(gl + 8);
      *(uint4*)&sWH[wmt * 128 + wc][wk]     = h0; *(uint4*)&sWH[wmt * 128 + wc][wk + 8] = h1;
      *(uint4*)&sWL[wmt * 128 + wc][wk]     = l0; *(uint4*)&sWL[wmt * 128 + wc][wk + 8] = l1;
    }
    __syncthreads();
    int wb = mat * 128 + cq * 32;
    bf16x8 bhi0 = *(const bf16x8*)&sWH[wb + col]     [kg*8];
    bf16x8 bhi1 = *(const bf16x8*)&sWH[wb + 16 + col][kg*8];
    bf16x8 blo0 = *(const bf16x8*)&sWL[wb + col]     [kg*8];
    bf16x8 blo1 = *(const bf16x8*)&sWL[wb + 16 + col][kg*8];
    #pragma unroll
    for (int m = 0; m < 4; m++){
      bf16x8 ahv = *(const bf16x8*)&sAH[m*16 + col][kg*8];
      bf16x8 alv = *(const bf16x8*)&sAL[m*16 + col][kg*8];
      acc[m][0] = __builtin_amdgcn_mfma_f32_16x16x32_bf16(ahv, bhi0, acc[m][0], 0, 0, 0);
      acc[m][0] = __builtin_amdgcn_mfma_f32_16x16x32_bf16(alv, bhi0, acc[m][0], 0, 0, 0);
      acc[m][0] = __builtin_amdgcn_mfma_f32_16x16x32_bf16(ahv, blo0, acc[m][0], 0, 0, 0);
      acc[m][1] = __builtin_amdgcn_mfma_f32_16x16x32_bf16(ahv, bhi1, acc[m][1], 0, 0, 0);
      acc[m][1] = __builtin_amdgcn_mfma_f32_16x16x32_bf16(alv, bhi1, acc[m][1], 0, 0, 0);
      acc[m][1] = __builtin_amdgcn_mfma_f32_16x16x32_bf16(ahv, blo1, acc[m][1], 0, 0, 0);
    }
  }
  u16* ob = mat ? xrb : xlb;
  #pragma unroll
  for (int m = 0; m < 4; m++){
    #pragma unroll
    for (int n = 0; n < 2; n++){
      #pragma unroll
      for (int r = 0; r < 4; r++){
        int row = r0 + m*16 + kg*4 + r;
        int c   = cq*32 + n*16 + col;
        if (row < nrows) ob[(size_t)row * 128 + c] = f2b(acc[m][n][r]);
      }
    }
  }
}

// ---------- edge kernel: half-channel LDS bounce; VGPR diet: only half-A xj pipelined,
// half-B xj loaded at loop top for the CURRENT tile (covered by MFMA-A + epilogue-A) ----------
__global__ __launch_bounds__(256) void k_edge(
    const int* __restrict__ ssrc, const int* __restrict__ sdst,
    const u16* __restrict__ ea2s,
    const u16* __restrict__ xlb, const u16* __restrict__ xrb,
    const float* __restrict__ We, const float* __restrict__ att,
    float2* __restrict__ pr2, int ntiles, int E)
{
  __shared__ float sDh[4][16][68];
  int wv = threadIdx.x >> 6, lane = threadIdx.x & 63;
  int col = lane & 15, kg = lane >> 4;
  int er = lane >> 2, q = lane & 3;

  bf16x8 bw[8];
  #pragma unroll
  for (int c = 0; c < 8; c++)
    #pragma unroll
    for (int j = 0; j < 8; j++)
      bw[c][j] = (short)f2b(We[(kg * 8 + j) * 128 + c * 16 + col]);
  u32 attp[16];
  #pragma unroll
  for (int h = 0; h < 2; h++)
    #pragma unroll
    for (int i = 0; i < 8; i++){
      int ch = h * 64 + q * 16 + 2 * i;
      attp[h * 8 + i] = (u32)f2b(att[ch]) | ((u32)f2b(att[ch + 1]) << 16);
    }

  int nw = gridDim.x * 4;
  int t = blockIdx.x * 4 + wv;
  if (t >= ntiles) return;

  // prologue: tile A (half-A xj only)
  int e0 = t * 16;
  int p = e0 + er;
  bf16x8 aA = *(const bf16x8*)(ea2s + (size_t)(e0 + col) * 32 + kg * 8);
  int snA = ssrc[p], dnA = sdst[p];
  const u16* xjA = xlb + (size_t)snA * 128;
  uint4 jAa0 = *(const uint4*)(xjA + q * 16), jAa1 = *(const uint4*)(xjA + q * 16 + 8);

  while (true){
    // current-tile loads issued early: xi half A, xj half B (latency covered below)
    const u16* xjr = xlb + (size_t)snA * 128;
    const u16* xir = xrb + (size_t)dnA * 128;
    uint4 iA0 = *(const uint4*)(xir + q * 16), iA1 = *(const uint4*)(xir + q * 16 + 8);
    uint4 jAb0 = *(const uint4*)(xjr + 64 + q * 16), jAb1 = *(const uint4*)(xjr + 64 + q * 16 + 8);
    uint4 iB0 = *(const uint4*)(xir + 64 + q * 16), iB1 = *(const uint4*)(xir + 64 + q * 16 + 8);

    // prefetch next tile (indices, ea2s, half-A xj)
    int t2 = t + nw;
    bool more = (t2 < ntiles);
    int tBc = more ? t2 : t;
    int eB = tBc * 16;
    int pB = eB + er;
    bf16x8 aB = *(const bf16x8*)(ea2s + (size_t)(eB + col) * 32 + kg * 8);
    int snB = ssrc[pB], dnB = sdst[pB];
    const u16* xjB = xlb + (size_t)snB * 128;
    uint4 jBa0 = *(const uint4*)(xjB + q * 16), jBa1 = *(const uint4*)(xjB + q * 16 + 8);

    // MFMA half A -> LDS
    #pragma unroll
    for (int c = 0; c < 4; c++){
      f32x4 d = __builtin_amdgcn_mfma_f32_16x16x32_bf16(aA, bw[c], (f32x4){0.f,0.f,0.f,0.f}, 0, 0, 0);
      #pragma unroll
      for (int r = 0; r < 4; r++)
        sDh[wv][kg * 4 + r][c * 16 + col] = d[r];
    }

    const float* dr = &sDh[wv][er][q * 16];

#define EPH(J0, J1, I0, I1, AB, ACC) { \
    float4 d0 = *(const float4*)(dr); \
    float4 d1 = *(const float4*)(dr + 4); \
    float4 d2 = *(const float4*)(dr + 8); \
    float4 d3 = *(const float4*)(dr + 12); \
    float v; \
    v = d0.x + bl(J0.x) + bl(I0.x); v = fmaxf(v, 0.2f*v); ACC = fmaf(v, bl(attp[AB+0]), ACC); \
    v = d0.y + bh(J0.x) + bh(I0.x); v = fmaxf(v, 0.2f*v); ACC = fmaf(v, bh(attp[AB+0]), ACC); \
    v = d0.z + bl(J0.y) + bl(I0.y); v = fmaxf(v, 0.2f*v); ACC = fmaf(v, bl(attp[AB+1]), ACC); \
    v = d0.w + bh(J0.y) + bh(I0.y); v = fmaxf(v, 0.2f*v); ACC = fmaf(v, bh(attp[AB+1]), ACC); \
    v = d1.x + bl(J0.z) + bl(I0.z); v = fmaxf(v, 0.2f*v); ACC = fmaf(v, bl(attp[AB+2]), ACC); \
    v = d1.y + bh(J0.z) + bh(I0.z); v = fmaxf(v, 0.2f*v); ACC = fmaf(v, bh(attp[AB+2]), ACC); \
    v = d1.z + bl(J0.w) + bl(I0.w); v = fmaxf(v, 0.2f*v); ACC = fmaf(v, bl(attp[AB+3]), ACC); \
    v = d1.w + bh(J0.w) + bh(I0.w); v = fmaxf(v, 0.2f*v); ACC = fmaf(v, bh(attp[AB+3]), ACC); \
    v = d2.x + bl(J1.x) + bl(I1.x); v = fmaxf(v, 0.2f*v); ACC = fmaf(v, bl(attp[AB+4]), ACC); \
    v = d2.y + bh(J1.x) + bh(I1.x); v = fmaxf(v, 0.2f*v); ACC = fmaf(v, bh(attp[AB+4]), ACC); \
    v = d2.z + bl(J1.y) + bl(I1.y); v = fmaxf(v, 0.2f*v); ACC = fmaf(v, bl(attp[AB+5]), ACC); \
    v = d2.w + bh(J1.y) + bh(I1.y); v = fmaxf(v, 0.2f*v); ACC = fmaf(v, bh(attp[AB+5]), ACC); \
    v = d3.x + bl(J1.z) + bl(I1.z); v = fmaxf(v, 0.2f*v); ACC = fmaf(v, bl(attp[AB+6]), ACC); \
    v = d3.y + bh(J1.z) + bh(I1.z); v = fmaxf(v, 0.2f*v); ACC = fmaf(v, bh(attp[AB+6]), ACC); \
    v = d3.z + bl(J1.w) + bl(I1.w); v = fmaxf(v, 0.2f*v); ACC = fmaf(v, bl(attp[AB+7]), ACC); \
    v = d3.w + bh(J1.w) + bh(I1.w); v = fmaxf(v, 0.2f*v); ACC = fmaf(v, bh(attp[AB+7]), ACC); }

    // epilogue half A -> head0 logit
    float hA = 0.f;
    EPH(jAa0, jAa1, iA0, iA1, 0, hA)
    hA += __shfl_xor(hA, 1);
    hA += __shfl_xor(hA, 2);

    // MFMA half B -> same LDS region (in-order DS: cannot pass half-A reads)
    #pragma unroll
    for (int c = 4; c < 8; c++){
      f32x4 d = __builtin_amdgcn_mfma_f32_16x16x32_bf16(aA, bw[c], (f32x4){0.f,0.f,0.f,0.f}, 0, 0, 0);
      #pragma unroll
      for (int r = 0; r < 4; r++)
        sDh[wv][kg * 4 + r][(c - 4) * 16 + col] = d[r];
    }

    // epilogue half B -> head1 logit
    float hB = 0.f;
    EPH(jAb0, jAb1, iB0, iB1, 8, hB)
    hB += __shfl_xor(hB, 1);
    hB += __shfl_xor(hB, 2);
#undef EPH

    if (q == 0 && p < E){
      pr2[p] = make_float2(__expf(fminf(hA, 80.f)), __expf(fminf(hB, 80.f)));
    }
    if (!more) break;
    t = t2; p = pB;
    aA = aB; snA = snB; dnA = dnB;
    jAa0 = jBa0; jAa1 = jBa1;
  }
}

// ---------- per-node reduce: 4 edges/step across wave, 16B lanes, 3-deep pipeline ----------
template<int RELU>
__global__ __launch_bounds__(256) void k_seg2(
    const int* __restrict__ seg, const int* __restrict__ ssrc,
    const float2* __restrict__ pr2,
    const u16* __restrict__ xlb, const float* __restrict__ bias,
    float* __restrict__ out, int N)
{
  int wid  = blockIdx.x * 4 + (threadIdx.x >> 6);
  int lane = threadIdx.x & 63;
  if (wid >= N) return;
  int eg = lane >> 4, cb = lane & 15, c0 = cb * 8;
  int hsel = cb >> 3;

  int p0 = seg[wid], p1 = seg[wid + 1];
  float s = 0.f;
  float o0 = 0.f, o1 = 0.f, o2 = 0.f, o3 = 0.f, o4 = 0.f, o5 = 0.f, o6 = 0.f, o7 = 0.f;

  if (p0 < p1){
#define LDB(PP, QV, XV) { \
    int ii = PP + eg; ii = (ii < p1) ? ii : (p1 - 1); \
    int sn = ssrc[ii]; \
    QV = pr2[ii]; \
    XV = *(const uint4*)(xlb + (size_t)sn * 128 + c0); }
    int p = p0;
    float2 qa; uint4 xa;
    LDB(p, qa, xa)
    int pBb = p + 4; int pBc = (pBb < p1) ? pBb : p;
    float2 qb; uint4 xb;
    LDB(pBc, qb, xb)
    while (true){
      int pCb = p + 8; int pCc = (pCb < p1) ? pCb : p;
      float2 qc; uint4 xc;
      LDB(pCc, qc, xc)
      float e = hsel ? qa.y : qa.x;
      if (p + eg >= p1) e = 0.f;
      s += e;
      o0 = fmaf(e, bl(xa.x), o0); o1 = fmaf(e, bh(xa.x), o1);
      o2 = fmaf(e, bl(xa.y), o2); o3 = fmaf(e, bh(xa.y), o3);
      o4 = fmaf(e, bl(xa.z), o4); o5 = fmaf(e, bh(xa.z), o5);
      o6 = fmaf(e, bl(xa.w), o6); o7 = fmaf(e, bh(xa.w), o7);
      if (p + 4 >= p1) break;
      p += 4;
      qa = qb; xa = xb;
      qb = qc; xb = xc;
    }
#undef LDB
  }
  s  += __shfl_xor(s, 16);  s  += __shfl_xor(s, 32);
  o0 += __shfl_xor(o0, 16); o0 += __shfl_xor(o0, 32);
  o1 += __shfl_xor(o1, 16); o1 += __shfl_xor(o1, 32);
  o2 += __shfl_xor(o2, 16); o2 += __shfl_xor(o2, 32);
  o3 += __shfl_xor(o3, 16); o3 += __shfl_xor(o3, 32);
  o4 += __shfl_xor(o4, 16); o4 += __shfl_xor(o4, 32);
  o5 += __shfl_xor(o5, 16); o5 += __shfl_xor(o5, 32);
  o6 += __shfl_xor(o6, 16); o6 += __shfl_xor(o6, 32);
  o7 += __shfl_xor(o7, 16); o7 += __shfl_xor(o7, 32);

  if (eg == 0){
    float inv = 1.0f / (s + 1e-16f);
    float4 b0 = *(const float4*)(bias + c0);
    float4 b1 = *(const float4*)(bias + c0 + 4);
    float r0 = fmaf(o0, inv, b0.x), r1 = fmaf(o1, inv, b0.y);
    float r2 = fmaf(o2, inv, b0.z), r3 = fmaf(o3, inv, b0.w);
    float r4 = fmaf(o4, inv, b1.x), r5 = fmaf(o5, inv, b1.y);
    float r6 = fmaf(o6, inv, b1.z), r7 = fmaf(o7, inv, b1.w);
    if (RELU){
      r0 = fmaxf(r0, 0.f); r1 = fmaxf(r1, 0.f); r2 = fmaxf(r2, 0.f); r3 = fmaxf(r3, 0.f);
      r4 = fmaxf(r4, 0.f); r5 = fmaxf(r5, 0.f); r6 = fmaxf(r6, 0.f); r7 = fmaxf(r7, 0.f);
    }
    *(float4*)(out + (size_t)wid * 128 + c0)     = make_float4(r0, r1, r2, r3);
    *(float4*)(out + (size_t)wid * 128 + c0 + 4) = make_float4(r4, r5, r6, r7);
  }
}

// ---------- launch ----------
extern "C" void kernel_launch(void* const* d_in, const int* in_sizes, int n_in,
                              void* d_out, int out_size, void* d_ws, size_t ws_size,
                              hipStream_t stream)
{
  const float* x     = (const float*)d_in[0];
  const int*   ei    = (const int*)  d_in[1];
  const float* eattr = (const float*)d_in[2];
  const float* Wp[3][5];
  for (int l = 0; l < 3; l++)
    for (int j = 0; j < 5; j++)
      Wp[l][j] = (const float*)d_in[3 + l * 5 + j];

  int N = in_sizes[0] / 128;
  int E = in_sizes[2] / 32;

  char* w = (char*)d_ws;
  auto alloc = [&](size_t bytes) -> char* {
    char* p = w; w += (bytes + 255) & ~(size_t)255; return p;
  };
  float* xr   = (float*)alloc((size_t)N * 128 * 4);   // inter-layer h buffer
  u16*   xlb  = (u16*)  alloc((size_t)N * 128 * 2);
  u16*   xrb  = (u16*)  alloc((size_t)N * 128 * 2);
  u16*   ea2s = (u16*)  alloc((size_t)(E + 64) * 32 * 2);    // dst-sorted bf16
  float2* prb = (float2*)alloc((size_t)E * 8);
  u16*   WtH  = (u16*)  alloc((size_t)6 * 16384 * 2);
  u16*   WtL  = (u16*)  alloc((size_t)6 * 16384 * 2);
  int* srcA   = (int*)alloc((size_t)E * 4);
  int* dstA   = (int*)alloc((size_t)E * 4);
  int* ssrc   = (int*)alloc((size_t)(E + 64) * 4);
  int* sdst   = (int*)alloc((size_t)(E + 64) * 4);
  int* seid   = (int*)alloc((size_t)E * 4);
  int* seg    = (int*)alloc((size_t)(N + 1) * 4);
  int* bsum   = (int*)alloc(1024 * 4);
  char* zbase = alloc((size_t)N * 4);      int* deg  = (int*)zbase;
  char* zcur  = alloc((size_t)N * 4);      int* cur  = (int*)zcur;
  char* zflag = alloc(256);                u32* flag = (u32*)zflag;
  size_t zspan = (size_t)(zflag + 256 - zbase);

  hipMemsetAsync(zbase, 0, zspan, stream);

  int ndet = (E < 16384) ? E : 16384;
  k_detect<<<(ndet + 255) / 256, 256, 0, stream>>>((const u32*)ei, ndet, flag);
  int gE = (E + 255) / 256;
  k_convhist<<<gE, 256, 0, stream>>>(ei, srcA, dstA, deg, E, flag);
  int nb = (N + 1023) / 1024;
  k_scan1<<<nb, 256, 0, stream>>>(deg, bsum, N, ssrc, sdst, ea2s + (size_t)E * 32, E);
  k_scan2<<<1, 1024, 0, stream>>>(bsum, nb, seg + N);
  k_scan3<<<nb, 256, 0, stream>>>(deg, bsum, seg, N);
  k_scatter<<<gE, 256, 0, stream>>>(srcA, dstA, seg, cur, ssrc, sdst, seid, E);
  k_sortb<<<(E * 8 + 255) / 256, 256, 0, stream>>>(seid, eattr, ea2s, E);
  dim3 gp(4, 4, 6);
  k_prepw<<<gp, 256, 0, stream>>>(Wp[0][0], Wp[0][1], Wp[1][0], Wp[1][1], Wp[2][0], Wp[2][1], WtH, WtL);

  int gS = (N + 3) / 4;
  int ntiles = (E + 15) / 16;
  int gEdge = (ntiles + 3) / 4; if (gEdge > 2048) gEdge = 2048;
  int gG2 = (N + 63) / 64;

  const float* hin = x;
  for (int l = 0; l < 3; l++){
    k_gemm2<<<gG2, 512, 0, stream>>>(hin, WtH + (size_t)l * 2 * 16384, WtL + (size_t)l * 2 * 16384, xlb, xrb, N);
    k_edge<<<gEdge, 256, 0, stream>>>(ssrc, sdst, ea2s, xlb, xrb, Wp[l][2], Wp[l][3], prb, ntiles, E);
    float* outp = (l == 2) ? (float*)d_out : xr;
    if (l == 2) k_seg2<0><<<gS, 256, 0, stream>>>(seg, ssrc, prb, xlb, Wp[l][4], outp, N);
    else        k_seg2<1><<<gS, 256, 0, stream>>>(seg, ssrc, prb, xlb, Wp[l][4], outp, N);
    hin = xr;
  }
}

// Round 24
// 439.880 us; speedup vs baseline: 1.0079x; 1.0079x over previous
//
#include <hip/hip_runtime.h>

typedef unsigned int u32;
typedef unsigned short u16;
typedef __attribute__((ext_vector_type(8))) short bf16x8;
typedef __attribute__((ext_vector_type(4))) float f32x4;

__device__ __forceinline__ u16 f2b(float f){
  u32 x = __float_as_uint(f);
  u32 r = (x + 0x7fffu + ((x >> 16) & 1u)) >> 16;
  return (u16)r;
}
__device__ __forceinline__ float b2f(u16 h){ return __uint_as_float((u32)h << 16); }
__device__ __forceinline__ float bl(u32 u){ return __uint_as_float(u << 16); }
__device__ __forceinline__ float bh(u32 u){ return __uint_as_float(u & 0xffff0000u); }

// ---------- preprocessing ----------

__global__ void k_detect(const u32* __restrict__ ei, int n, u32* __restrict__ flag){
  int t = blockIdx.x * blockDim.x + threadIdx.x;
  u32 v = 0;
  if (t < n) v = ei[2 * t + 1];
  unsigned long long b = __ballot(v != 0u);
  if ((threadIdx.x & 63) == 0 && b) atomicOr(flag, 1u);
}

// fused: index convert + degree histogram
__global__ void k_convhist(const int* __restrict__ ei, int* __restrict__ src, int* __restrict__ dst,
                           int* __restrict__ deg, int E, const u32* __restrict__ flag){
  int e = blockIdx.x * blockDim.x + threadIdx.x;
  if (e >= E) return;
  bool is64 = (*flag == 0u);
  int s, d;
  if (is64){ s = ei[2 * e]; d = ei[2 * (E + e)]; }
  else     { s = ei[e];     d = ei[E + e]; }
  src[e] = s; dst[e] = d;
  atomicAdd(&deg[d], 1);
}

// hierarchical scan; block 0 also zeroes the pad tails
__global__ __launch_bounds__(256) void k_scan1(const int* __restrict__ deg, int* __restrict__ bsum, int n,
                                               int* __restrict__ ssrc, int* __restrict__ sdst,
                                               u16* __restrict__ ea2s_pad, int E){
  int b = blockIdx.x, t = threadIdx.x, lane = t & 63, wv = t >> 6;
  if (b == 0){
    if (t < 64){ ssrc[E + t] = 0; sdst[E + t] = 0; }
    ((uint4*)ea2s_pad)[t] = make_uint4(0, 0, 0, 0);
  }
  int i0 = b * 1024 + t * 4;
  int4 v = make_int4(0,0,0,0);
  if (i0 + 3 < n) v = *(const int4*)(deg + i0);
  else { if (i0 < n) v.x = deg[i0]; if (i0+1 < n) v.y = deg[i0+1]; if (i0+2 < n) v.z = deg[i0+2]; }
  int s = v.x + v.y + v.z + v.w;
  #pragma unroll
  for (int off = 1; off < 64; off <<= 1) s += __shfl_xor(s, off);
  __shared__ int ws[4];
  if (lane == 0) ws[wv] = s;
  __syncthreads();
  if (t == 0) bsum[b] = ws[0] + ws[1] + ws[2] + ws[3];
}

__global__ __launch_bounds__(1024) void k_scan2(int* __restrict__ bsum, int nb, int* __restrict__ segN){
  int t = threadIdx.x, lane = t & 63, w = t >> 6;
  int v = (t < nb) ? bsum[t] : 0;
  int x = v;
  #pragma unroll
  for (int off = 1; off < 64; off <<= 1){
    int y = __shfl_up(x, off);
    if (lane >= off) x += y;
  }
  __shared__ int wsum[16];
  if (lane == 63) wsum[w] = x;
  __syncthreads();
  if (w == 0 && lane < 16){
    int sv = wsum[lane];
    #pragma unroll
    for (int off = 1; off < 16; off <<= 1){
      int y = __shfl_up(sv, off);
      if (lane >= off) sv += y;
    }
    wsum[lane] = sv;
  }
  __syncthreads();
  int woff = (w > 0) ? wsum[w - 1] : 0;
  if (t < nb) bsum[t] = woff + x - v;
  if (t == 0) *segN = wsum[15];
}

__global__ __launch_bounds__(256) void k_scan3(const int* __restrict__ deg, const int* __restrict__ bsum,
                                               int* __restrict__ seg, int n){
  int b = blockIdx.x, t = threadIdx.x, lane = t & 63, wv = t >> 6;
  int i0 = b * 1024 + t * 4;
  int4 v = make_int4(0,0,0,0);
  if (i0 + 3 < n) v = *(const int4*)(deg + i0);
  else { if (i0 < n) v.x = deg[i0]; if (i0+1 < n) v.y = deg[i0+1]; if (i0+2 < n) v.z = deg[i0+2]; }
  int s = v.x + v.y + v.z + v.w;
  int x = s;
  #pragma unroll
  for (int off = 1; off < 64; off <<= 1){
    int y = __shfl_up(x, off);
    if (lane >= off) x += y;
  }
  __shared__ int ws[4];
  if (lane == 63) ws[wv] = x;
  __syncthreads();
  int woff = 0;
  #pragma unroll
  for (int k = 0; k < 4; k++) if (k < wv) woff += ws[k];
  int base = bsum[b] + woff + (x - s);
  if (i0 < n)     seg[i0]     = base;
  if (i0+1 < n)   seg[i0+1]   = base + v.x;
  if (i0+2 < n)   seg[i0+2]   = base + v.x + v.y;
  if (i0+3 < n)   seg[i0+3]   = base + v.x + v.y + v.z;
}

// scatter: 12B {src, dst, eid} per edge to sorted position
__global__ void k_scatter(const int* __restrict__ src, const int* __restrict__ dst,
                          const int* __restrict__ seg, int* __restrict__ cur,
                          int* __restrict__ ssrc, int* __restrict__ sdst,
                          int* __restrict__ seid, int E){
  int e = blockIdx.x * blockDim.x + threadIdx.x;
  if (e >= E) return;
  int d = dst[e];
  int pos = seg[d] + atomicAdd(&cur[d], 1);
  ssrc[pos] = src[e];
  sdst[pos] = d;
  seid[pos] = e;
}

// sort + convert: read eattr f32 rows via seid, write dst-sorted bf16 rows coalesced
__global__ void k_sortb(const int* __restrict__ seid, const float* __restrict__ eattr,
                        u16* __restrict__ ea2s, int E){
  int t = blockIdx.x * blockDim.x + threadIdx.x;
  int e = t >> 3, j = t & 7;
  if (e >= E) return;
  int eid = seid[e];
  float4 v = *(const float4*)(eattr + (size_t)eid * 32 + j * 4);
  u32 p0 = (u32)f2b(v.x) | ((u32)f2b(v.y) << 16);
  u32 p1 = (u32)f2b(v.z) | ((u32)f2b(v.w) << 16);
  *(uint2*)(ea2s + (size_t)e * 32 + j * 4) = make_uint2(p0, p1);
}

// ---------- W prep: transpose + bf16 hi/lo split ----------
__global__ __launch_bounds__(256) void k_prepw(
    const float* __restrict__ W0, const float* __restrict__ W1, const float* __restrict__ W2,
    const float* __restrict__ W3, const float* __restrict__ W4, const float* __restrict__ W5,
    u16* __restrict__ WtH, u16* __restrict__ WtL)
{
  int mat = blockIdx.z;
  const float* W = (mat == 0) ? W0 : (mat == 1) ? W1 : (mat == 2) ? W2 :
                   (mat == 3) ? W3 : (mat == 4) ? W4 : W5;
  __shared__ float tile[32][33];
  int kt = blockIdx.x * 32, ct = blockIdx.y * 32;
  int tr = threadIdx.x & 31, ti = threadIdx.x >> 5;
  #pragma unroll
  for (int j = 0; j < 4; j++){
    int kk = ti + 8 * j;
    tile[kk][tr] = W[(size_t)(kt + kk) * 128 + ct + tr];
  }
  __syncthreads();
  #pragma unroll
  for (int j = 0; j < 4; j++){
    int cc = ti + 8 * j;
    float v = tile[tr][cc];
    u16 hi = f2b(v);
    u16 lo = f2b(v - b2f(hi));
    size_t o = (size_t)mat * 16384 + (size_t)(ct + cc) * 128 + kt + tr;
    WtH[o] = hi;
    WtL[o] = lo;
  }
}

// ---------- node transform via MFMA (bf16x3 split), BOTH mats in one block ----------
__global__ __launch_bounds__(512) void k_gemm2(
    const float* __restrict__ A,
    const u16* __restrict__ WtH, const u16* __restrict__ WtL,
    u16* __restrict__ xlb, u16* __restrict__ xrb, int nrows)
{
  __shared__ u16 sAH[64][32], sAL[64][32];
  __shared__ u16 sWH[256][32], sWL[256][32];
  int t = threadIdx.x, wv = t >> 6, lane = t & 63;
  int col = lane & 15, kg = lane >> 4;
  int mat = wv >> 2, cq = wv & 3;
  int r0 = blockIdx.x * 64;

  f32x4 acc[4][2];
  #pragma unroll
  for (int m = 0; m < 4; m++)
    #pragma unroll
    for (int n = 0; n < 2; n++)
      acc[m][n] = (f32x4){0.f, 0.f, 0.f, 0.f};

  int ar = t >> 3, ak = (t & 7) << 2;
  int wmt = t >> 8, wtt = t & 255;
  int wc = wtt >> 1, wk = (wtt & 1) << 4;

  for (int kh = 0; kh < 4; kh++){
    __syncthreads();
    {
      int gr = r0 + ar;
      const float* ap = A + (size_t)gr * 128 + kh * 32 + ak;
      float4 va = {0,0,0,0};
      if (gr < nrows) va = *(const float4*)ap;
      u16 h0 = f2b(va.x), h1 = f2b(va.y), h2 = f2b(va.z), h3 = f2b(va.w);
      u16 l0 = f2b(va.x - b2f(h0)), l1 = f2b(va.y - b2f(h1));
      u16 l2 = f2b(va.z - b2f(h2)), l3 = f2b(va.w - b2f(h3));
      *(uint2*)&sAH[ar][ak] = make_uint2((u32)h0 | ((u32)h1 << 16), (u32)h2 | ((u32)h3 << 16));
      *(uint2*)&sAL[ar][ak] = make_uint2((u32)l0 | ((u32)l1 << 16), (u32)l2 | ((u32)l3 << 16));
    }
    {
      const u16* gh = WtH + (size_t)wmt * 16384 + (size_t)wc * 128 + kh * 32 + wk;
      const u16* gl = WtL + (size_t)wmt * 16384 + (size_t)wc * 128 + kh * 32 + wk;
      uint4 h0 = *(const uint4*)gh, h1 = *(const uint4*)(gh + 8);
      uint4 l0 = *(const uint4*)gl, l1 = *(const uint4*)(gl + 8);
      *(uint4*)&sWH[wmt * 128 + wc][wk]     = h0; *(uint4*)&sWH[wmt * 128 + wc][wk + 8] = h1;
      *(uint4*)&sWL[wmt * 128 + wc][wk]     = l0; *(uint4*)&sWL[wmt * 128 + wc][wk + 8] = l1;
    }
    __syncthreads();
    int wb = mat * 128 + cq * 32;
    bf16x8 bhi0 = *(const bf16x8*)&sWH[wb + col]     [kg*8];
    bf16x8 bhi1 = *(const bf16x8*)&sWH[wb + 16 + col][kg*8];
    bf16x8 blo0 = *(const bf16x8*)&sWL[wb + col]     [kg*8];
    bf16x8 blo1 = *(const bf16x8*)&sWL[wb + 16 + col][kg*8];
    #pragma unroll
    for (int m = 0; m < 4; m++){
      bf16x8 ahv = *(const bf16x8*)&sAH[m*16 + col][kg*8];
      bf16x8 alv = *(const bf16x8*)&sAL[m*16 + col][kg*8];
      acc[m][0] = __builtin_amdgcn_mfma_f32_16x16x32_bf16(ahv, bhi0, acc[m][0], 0, 0, 0);
      acc[m][0] = __builtin_amdgcn_mfma_f32_16x16x32_bf16(alv, bhi0, acc[m][0], 0, 0, 0);
      acc[m][0] = __builtin_amdgcn_mfma_f32_16x16x32_bf16(ahv, blo0, acc[m][0], 0, 0, 0);
      acc[m][1] = __builtin_amdgcn_mfma_f32_16x16x32_bf16(ahv, bhi1, acc[m][1], 0, 0, 0);
      acc[m][1] = __builtin_amdgcn_mfma_f32_16x16x32_bf16(alv, bhi1, acc[m][1], 0, 0, 0);
      acc[m][1] = __builtin_amdgcn_mfma_f32_16x16x32_bf16(ahv, blo1, acc[m][1], 0, 0, 0);
    }
  }
  u16* ob = mat ? xrb : xlb;
  #pragma unroll
  for (int m = 0; m < 4; m++){
    #pragma unroll
    for (int n = 0; n < 2; n++){
      #pragma unroll
      for (int r = 0; r < 4; r++){
        int row = r0 + m*16 + kg*4 + r;
        int c   = cq*32 + n*16 + col;
        if (row < nrows) ob[(size_t)row * 128 + c] = f2b(acc[m][n][r]);
      }
    }
  }
}

// ---------- edge kernel: half-channel LDS bounce (17.4 KB), 2-deep xj pipeline ----------
// per tile: half A = ch 0..63 (head0), half B = ch 64..127 (head1). Epilogue lane
// (er,q) handles 16 ch per half. Per-wave DS is in-order: half-B writes cannot pass
// half-A reads, so no barrier needed.
__global__ __launch_bounds__(256) void k_edge(
    const int* __restrict__ ssrc, const int* __restrict__ sdst,
    const u16* __restrict__ ea2s,
    const u16* __restrict__ xlb, const u16* __restrict__ xrb,
    const float* __restrict__ We, const float* __restrict__ att,
    float2* __restrict__ pr2, int ntiles, int E)
{
  __shared__ float sDh[4][16][68];
  int wv = threadIdx.x >> 6, lane = threadIdx.x & 63;
  int col = lane & 15, kg = lane >> 4;
  int er = lane >> 2, q = lane & 3;

  bf16x8 bw[8];
  #pragma unroll
  for (int c = 0; c < 8; c++)
    #pragma unroll
    for (int j = 0; j < 8; j++)
      bw[c][j] = (short)f2b(We[(kg * 8 + j) * 128 + c * 16 + col]);
  // attp[h*8+i] packs att channels h*64 + q*16 + 2i, +1
  u32 attp[16];
  #pragma unroll
  for (int h = 0; h < 2; h++)
    #pragma unroll
    for (int i = 0; i < 8; i++){
      int ch = h * 64 + q * 16 + 2 * i;
      attp[h * 8 + i] = (u32)f2b(att[ch]) | ((u32)f2b(att[ch + 1]) << 16);
    }

  int nw = gridDim.x * 4;
  int t = blockIdx.x * 4 + wv;
  if (t >= ntiles) return;

  // prologue: tile A (both halves of xj)
  int e0 = t * 16;
  int p = e0 + er;
  bf16x8 aA = *(const bf16x8*)(ea2s + (size_t)(e0 + col) * 32 + kg * 8);
  int snA = ssrc[p], dnA = sdst[p];
  const u16* xjA = xlb + (size_t)snA * 128;
  uint4 jAa0 = *(const uint4*)(xjA + q * 16),      jAa1 = *(const uint4*)(xjA + q * 16 + 8);
  uint4 jAb0 = *(const uint4*)(xjA + 64 + q * 16), jAb1 = *(const uint4*)(xjA + 64 + q * 16 + 8);

  while (true){
    const u16* xir = xrb + (size_t)dnA * 128;
    uint4 iA0 = *(const uint4*)(xir + q * 16), iA1 = *(const uint4*)(xir + q * 16 + 8);

    // prefetch next tile (indices, ea2s, both xj halves)
    int t2 = t + nw;
    bool more = (t2 < ntiles);
    int tBc = more ? t2 : t;
    int eB = tBc * 16;
    int pB = eB + er;
    bf16x8 aB = *(const bf16x8*)(ea2s + (size_t)(eB + col) * 32 + kg * 8);
    int snB = ssrc[pB], dnB = sdst[pB];
    const u16* xjB = xlb + (size_t)snB * 128;
    uint4 jBa0 = *(const uint4*)(xjB + q * 16),      jBa1 = *(const uint4*)(xjB + q * 16 + 8);
    uint4 jBb0 = *(const uint4*)(xjB + 64 + q * 16), jBb1 = *(const uint4*)(xjB + 64 + q * 16 + 8);

    // MFMA half A -> LDS
    #pragma unroll
    for (int c = 0; c < 4; c++){
      f32x4 d = __builtin_amdgcn_mfma_f32_16x16x32_bf16(aA, bw[c], (f32x4){0.f,0.f,0.f,0.f}, 0, 0, 0);
      #pragma unroll
      for (int r = 0; r < 4; r++)
        sDh[wv][kg * 4 + r][c * 16 + col] = d[r];
    }

    const float* dr = &sDh[wv][er][q * 16];

#define EPH(J0, J1, I0, I1, AB, ACC) { \
    float4 d0 = *(const float4*)(dr); \
    float4 d1 = *(const float4*)(dr + 4); \
    float4 d2 = *(const float4*)(dr + 8); \
    float4 d3 = *(const float4*)(dr + 12); \
    float v; \
    v = d0.x + bl(J0.x) + bl(I0.x); v = fmaxf(v, 0.2f*v); ACC = fmaf(v, bl(attp[AB+0]), ACC); \
    v = d0.y + bh(J0.x) + bh(I0.x); v = fmaxf(v, 0.2f*v); ACC = fmaf(v, bh(attp[AB+0]), ACC); \
    v = d0.z + bl(J0.y) + bl(I0.y); v = fmaxf(v, 0.2f*v); ACC = fmaf(v, bl(attp[AB+1]), ACC); \
    v = d0.w + bh(J0.y) + bh(I0.y); v = fmaxf(v, 0.2f*v); ACC = fmaf(v, bh(attp[AB+1]), ACC); \
    v = d1.x + bl(J0.z) + bl(I0.z); v = fmaxf(v, 0.2f*v); ACC = fmaf(v, bl(attp[AB+2]), ACC); \
    v = d1.y + bh(J0.z) + bh(I0.z); v = fmaxf(v, 0.2f*v); ACC = fmaf(v, bh(attp[AB+2]), ACC); \
    v = d1.z + bl(J0.w) + bl(I0.w); v = fmaxf(v, 0.2f*v); ACC = fmaf(v, bl(attp[AB+3]), ACC); \
    v = d1.w + bh(J0.w) + bh(I0.w); v = fmaxf(v, 0.2f*v); ACC = fmaf(v, bh(attp[AB+3]), ACC); \
    v = d2.x + bl(J1.x) + bl(I1.x); v = fmaxf(v, 0.2f*v); ACC = fmaf(v, bl(attp[AB+4]), ACC); \
    v = d2.y + bh(J1.x) + bh(I1.x); v = fmaxf(v, 0.2f*v); ACC = fmaf(v, bh(attp[AB+4]), ACC); \
    v = d2.z + bl(J1.y) + bl(I1.y); v = fmaxf(v, 0.2f*v); ACC = fmaf(v, bl(attp[AB+5]), ACC); \
    v = d2.w + bh(J1.y) + bh(I1.y); v = fmaxf(v, 0.2f*v); ACC = fmaf(v, bh(attp[AB+5]), ACC); \
    v = d3.x + bl(J1.z) + bl(I1.z); v = fmaxf(v, 0.2f*v); ACC = fmaf(v, bl(attp[AB+6]), ACC); \
    v = d3.y + bh(J1.z) + bh(I1.z); v = fmaxf(v, 0.2f*v); ACC = fmaf(v, bh(attp[AB+6]), ACC); \
    v = d3.z + bl(J1.w) + bl(I1.w); v = fmaxf(v, 0.2f*v); ACC = fmaf(v, bl(attp[AB+7]), ACC); \
    v = d3.w + bh(J1.w) + bh(I1.w); v = fmaxf(v, 0.2f*v); ACC = fmaf(v, bh(attp[AB+7]), ACC); }

    // epilogue half A -> head0 logit
    float hA = 0.f;
    EPH(jAa0, jAa1, iA0, iA1, 0, hA)
    hA += __shfl_xor(hA, 1);
    hA += __shfl_xor(hA, 2);

    // xi half B (L1-resident)
    uint4 iB0 = *(const uint4*)(xir + 64 + q * 16), iB1 = *(const uint4*)(xir + 64 + q * 16 + 8);

    // MFMA half B -> same LDS region (in-order DS: cannot pass half-A reads)
    #pragma unroll
    for (int c = 4; c < 8; c++){
      f32x4 d = __builtin_amdgcn_mfma_f32_16x16x32_bf16(aA, bw[c], (f32x4){0.f,0.f,0.f,0.f}, 0, 0, 0);
      #pragma unroll
      for (int r = 0; r < 4; r++)
        sDh[wv][kg * 4 + r][(c - 4) * 16 + col] = d[r];
    }

    // epilogue half B -> head1 logit
    float hB = 0.f;
    EPH(jAb0, jAb1, iB0, iB1, 8, hB)
    hB += __shfl_xor(hB, 1);
    hB += __shfl_xor(hB, 2);
#undef EPH

    if (q == 0 && p < E){
      pr2[p] = make_float2(__expf(fminf(hA, 80.f)), __expf(fminf(hB, 80.f)));
    }
    if (!more) break;
    t = t2; p = pB;
    aA = aB; dnA = dnB;
    jAa0 = jBa0; jAa1 = jBa1; jAb0 = jBb0; jAb1 = jBb1;
  }
}

// ---------- per-node reduce: 4 edges/step across wave, 16B lanes, 3-deep pipeline ----------
template<int RELU>
__global__ __launch_bounds__(256) void k_seg2(
    const int* __restrict__ seg, const int* __restrict__ ssrc,
    const float2* __restrict__ pr2,
    const u16* __restrict__ xlb, const float* __restrict__ bias,
    float* __restrict__ out, int N)
{
  int wid  = blockIdx.x * 4 + (threadIdx.x >> 6);
  int lane = threadIdx.x & 63;
  if (wid >= N) return;
  int eg = lane >> 4, cb = lane & 15, c0 = cb * 8;
  int hsel = cb >> 3;

  int p0 = seg[wid], p1 = seg[wid + 1];
  float s = 0.f;
  float o0 = 0.f, o1 = 0.f, o2 = 0.f, o3 = 0.f, o4 = 0.f, o5 = 0.f, o6 = 0.f, o7 = 0.f;

  if (p0 < p1){
#define LDB(PP, QV, XV) { \
    int ii = PP + eg; ii = (ii < p1) ? ii : (p1 - 1); \
    int sn = ssrc[ii]; \
    QV = pr2[ii]; \
    XV = *(const uint4*)(xlb + (size_t)sn * 128 + c0); }
    int p = p0;
    float2 qa; uint4 xa;
    LDB(p, qa, xa)
    int pBb = p + 4; int pBc = (pBb < p1) ? pBb : p;
    float2 qb; uint4 xb;
    LDB(pBc, qb, xb)
    while (true){
      int pCb = p + 8; int pCc = (pCb < p1) ? pCb : p;
      float2 qc; uint4 xc;
      LDB(pCc, qc, xc)
      float e = hsel ? qa.y : qa.x;
      if (p + eg >= p1) e = 0.f;
      s += e;
      o0 = fmaf(e, bl(xa.x), o0); o1 = fmaf(e, bh(xa.x), o1);
      o2 = fmaf(e, bl(xa.y), o2); o3 = fmaf(e, bh(xa.y), o3);
      o4 = fmaf(e, bl(xa.z), o4); o5 = fmaf(e, bh(xa.z), o5);
      o6 = fmaf(e, bl(xa.w), o6); o7 = fmaf(e, bh(xa.w), o7);
      if (p + 4 >= p1) break;
      p += 4;
      qa = qb; xa = xb;
      qb = qc; xb = xc;
    }
#undef LDB
  }
  s  += __shfl_xor(s, 16);  s  += __shfl_xor(s, 32);
  o0 += __shfl_xor(o0, 16); o0 += __shfl_xor(o0, 32);
  o1 += __shfl_xor(o1, 16); o1 += __shfl_xor(o1, 32);
  o2 += __shfl_xor(o2, 16); o2 += __shfl_xor(o2, 32);
  o3 += __shfl_xor(o3, 16); o3 += __shfl_xor(o3, 32);
  o4 += __shfl_xor(o4, 16); o4 += __shfl_xor(o4, 32);
  o5 += __shfl_xor(o5, 16); o5 += __shfl_xor(o5, 32);
  o6 += __shfl_xor(o6, 16); o6 += __shfl_xor(o6, 32);
  o7 += __shfl_xor(o7, 16); o7 += __shfl_xor(o7, 32);

  if (eg == 0){
    float inv = 1.0f / (s + 1e-16f);
    float4 b0 = *(const float4*)(bias + c0);
    float4 b1 = *(const float4*)(bias + c0 + 4);
    float r0 = fmaf(o0, inv, b0.x), r1 = fmaf(o1, inv, b0.y);
    float r2 = fmaf(o2, inv, b0.z), r3 = fmaf(o3, inv, b0.w);
    float r4 = fmaf(o4, inv, b1.x), r5 = fmaf(o5, inv, b1.y);
    float r6 = fmaf(o6, inv, b1.z), r7 = fmaf(o7, inv, b1.w);
    if (RELU){
      r0 = fmaxf(r0, 0.f); r1 = fmaxf(r1, 0.f); r2 = fmaxf(r2, 0.f); r3 = fmaxf(r3, 0.f);
      r4 = fmaxf(r4, 0.f); r5 = fmaxf(r5, 0.f); r6 = fmaxf(r6, 0.f); r7 = fmaxf(r7, 0.f);
    }
    *(float4*)(out + (size_t)wid * 128 + c0)     = make_float4(r0, r1, r2, r3);
    *(float4*)(out + (size_t)wid * 128 + c0 + 4) = make_float4(r4, r5, r6, r7);
  }
}

// ---------- launch ----------
extern "C" void kernel_launch(void* const* d_in, const int* in_sizes, int n_in,
                              void* d_out, int out_size, void* d_ws, size_t ws_size,
                              hipStream_t stream)
{
  const float* x     = (const float*)d_in[0];
  const int*   ei    = (const int*)  d_in[1];
  const float* eattr = (const float*)d_in[2];
  const float* Wp[3][5];
  for (int l = 0; l < 3; l++)
    for (int j = 0; j < 5; j++)
      Wp[l][j] = (const float*)d_in[3 + l * 5 + j];

  int N = in_sizes[0] / 128;
  int E = in_sizes[2] / 32;

  char* w = (char*)d_ws;
  auto alloc = [&](size_t bytes) -> char* {
    char* p = w; w += (bytes + 255) & ~(size_t)255; return p;
  };
  float* xr   = (float*)alloc((size_t)N * 128 * 4);   // inter-layer h buffer
  u16*   xlb  = (u16*)  alloc((size_t)N * 128 * 2);
  u16*   xrb  = (u16*)  alloc((size_t)N * 128 * 2);
  u16*   ea2s = (u16*)  alloc((size_t)(E + 64) * 32 * 2);    // dst-sorted bf16
  float2* prb = (float2*)alloc((size_t)E * 8);
  u16*   WtH  = (u16*)  alloc((size_t)6 * 16384 * 2);
  u16*   WtL  = (u16*)  alloc((size_t)6 * 16384 * 2);
  int* srcA   = (int*)alloc((size_t)E * 4);
  int* dstA   = (int*)alloc((size_t)E * 4);
  int* ssrc   = (int*)alloc((size_t)(E + 64) * 4);
  int* sdst   = (int*)alloc((size_t)(E + 64) * 4);
  int* seid   = (int*)alloc((size_t)E * 4);
  int* seg    = (int*)alloc((size_t)(N + 1) * 4);
  int* bsum   = (int*)alloc(1024 * 4);
  char* zbase = alloc((size_t)N * 4);      int* deg  = (int*)zbase;
  char* zcur  = alloc((size_t)N * 4);      int* cur  = (int*)zcur;
  char* zflag = alloc(256);                u32* flag = (u32*)zflag;
  size_t zspan = (size_t)(zflag + 256 - zbase);

  hipMemsetAsync(zbase, 0, zspan, stream);

  int ndet = (E < 16384) ? E : 16384;
  k_detect<<<(ndet + 255) / 256, 256, 0, stream>>>((const u32*)ei, ndet, flag);
  int gE = (E + 255) / 256;
  k_convhist<<<gE, 256, 0, stream>>>(ei, srcA, dstA, deg, E, flag);
  int nb = (N + 1023) / 1024;
  k_scan1<<<nb, 256, 0, stream>>>(deg, bsum, N, ssrc, sdst, ea2s + (size_t)E * 32, E);
  k_scan2<<<1, 1024, 0, stream>>>(bsum, nb, seg + N);
  k_scan3<<<nb, 256, 0, stream>>>(deg, bsum, seg, N);
  k_scatter<<<gE, 256, 0, stream>>>(srcA, dstA, seg, cur, ssrc, sdst, seid, E);
  k_sortb<<<(E * 8 + 255) / 256, 256, 0, stream>>>(seid, eattr, ea2s, E);
  dim3 gp(4, 4, 6);
  k_prepw<<<gp, 256, 0, stream>>>(Wp[0][0], Wp[0][1], Wp[1][0], Wp[1][1], Wp[2][0], Wp[2][1], WtH, WtL);

  int gS = (N + 3) / 4;
  int ntiles = (E + 15) / 16;
  int gEdge = (ntiles + 3) / 4; if (gEdge > 2048) gEdge = 2048;
  int gG2 = (N + 63) / 64;

  const float* hin = x;
  for (int l = 0; l < 3; l++){
    k_gemm2<<<gG2, 512, 0, stream>>>(hin, WtH + (size_t)l * 2 * 16384, WtL + (size_t)l * 2 * 16384, xlb, xrb, N);
    k_edge<<<gEdge, 256, 0, stream>>>(ssrc, sdst, ea2s, xlb, xrb, Wp[l][2], Wp[l][3], prb, ntiles, E);
    float* outp = (l == 2) ? (float*)d_out : xr;
    if (l == 2) k_seg2<0><<<gS, 256, 0, stream>>>(seg, ssrc, prb, xlb, Wp[l][4], outp, N);
    else        k_seg2<1><<<gS, 256, 0, stream>>>(seg, ssrc, prb, xlb, Wp[l][4], outp, N);
    hin = xr;
  }
}